// Round 3
// baseline (1128.054 us; speedup 1.0000x reference)
//
#include <hip/hip_runtime.h>
#include <hip/hip_bf16.h>

// Attention forward, MI355X (gfx950).
// Inputs are fp32 (per reference dtypes); output fp32.
// Internally: convert to bf16 once, run MFMA pipeline:
//   per batch: convert x -> 3x gemm_bt (Q/K/V) -> flash attn -> gemm_bt (out, fp32).
// Layouts (verified per guide m89/m74/m120):
//   A-frag: A[m=lane&15][k=(lane>>4)*8+j]   (8 bf16 = short8)
//   B-frag: B[n=lane&15][k=(lane>>4)*8+j]
//   C/D:    col=lane&15, row=(lane>>4)*4+reg

typedef short short8 __attribute__((ext_vector_type(8)));
typedef float f32x4 __attribute__((ext_vector_type(4)));

#define MFMA16(a, b, c) __builtin_amdgcn_mfma_f32_16x16x32_bf16((a), (b), (c), 0, 0, 0)

static __device__ __forceinline__ ushort f2bf(float f) {
  union { __hip_bfloat16 h; ushort u; } cv;
  cv.h = __float2bfloat16(f);
  return cv.u;
}

static __device__ __forceinline__ void store_out(float* p, float v) { *p = v; }
static __device__ __forceinline__ void store_out(__hip_bfloat16* p, float v) {
  *p = __float2bfloat16(v);
}

// fp32 -> bf16 conversion, vectorized (n multiple of 4).
__global__ __launch_bounds__(256) void f32_to_bf16_kernel(
    const float* __restrict__ in, ushort* __restrict__ out, int n4) {
  int i = blockIdx.x * blockDim.x + threadIdx.x;
  if (i >= n4) return;
  const float4 v = ((const float4*)in)[i];
  ushort4 o;
  o.x = f2bf(v.x); o.y = f2bf(v.y); o.z = f2bf(v.z); o.w = f2bf(v.w);
  ((ushort4*)out)[i] = o;
}

// C[M,N] = A[M,K] (bf16) * B[N,K]^T (bf16), fp32 accumulate, OUT_T output.
// Block = 256 threads = 4 waves; block tile 128x128, wave tile 64x64.
template <typename OUT_T>
__global__ __launch_bounds__(256) void gemm_bt_kernel(
    const ushort* __restrict__ A, const ushort* __restrict__ B,
    OUT_T* __restrict__ C, int M, int N, int K) {
  const int lane = threadIdx.x & 63;
  const int wave = threadIdx.x >> 6;
  const int lm = lane & 15;
  const int lk = (lane >> 4) * 8;
  const int m0 = blockIdx.y * 128 + (wave >> 1) * 64;
  const int n0 = blockIdx.x * 128 + (wave & 1) * 64;

  f32x4 acc[4][4] = {};
  for (int k0 = 0; k0 < K; k0 += 32) {
    short8 a[4], b[4];
#pragma unroll
    for (int i = 0; i < 4; ++i)
      a[i] = *(const short8*)(A + (size_t)(m0 + i * 16 + lm) * K + k0 + lk);
#pragma unroll
    for (int i = 0; i < 4; ++i)
      b[i] = *(const short8*)(B + (size_t)(n0 + i * 16 + lm) * K + k0 + lk);
#pragma unroll
    for (int i = 0; i < 4; ++i)
#pragma unroll
      for (int j = 0; j < 4; ++j)
        acc[i][j] = MFMA16(a[i], b[j], acc[i][j]);
  }

  const int rq = (lane >> 4) * 4;
#pragma unroll
  for (int i = 0; i < 4; ++i)
#pragma unroll
    for (int j = 0; j < 4; ++j)
#pragma unroll
      for (int r = 0; r < 4; ++r)
        store_out(&C[(size_t)(m0 + i * 16 + rq + r) * N + n0 + j * 16 + lm],
                  acc[i][j][r]);
}

// Flash-style causal attention for ONE batch, head-interleaved bf16 Q/K/V
// (row stride 1024, head h occupies cols h*64..h*64+63).
// Grid: (N_CTX/64, NUM_HEADS). One block = 4 waves = 64 q-rows per head.
__global__ __launch_bounds__(256) void flash_kernel(
    const ushort* __restrict__ Q, const ushort* __restrict__ Km,
    const ushort* __restrict__ V, __hip_bfloat16* __restrict__ Z) {
  const int qb = blockIdx.x * 64;
  const int head = blockIdx.y;
  const int tid = threadIdx.x;
  const int wave = tid >> 6, lane = tid & 63;
  const int lm = lane & 15, quad = lane >> 4;

  __shared__ __align__(16) ushort vt[64 * 40];     // V^T tile, stride 40
  __shared__ __align__(16) ushort pb[4][16 * 40];  // per-wave P tile

  const size_t base = (size_t)head * 64;
  const int qrow = qb + wave * 16;

  short8 qa[2];
#pragma unroll
  for (int kk = 0; kk < 2; ++kk)
    qa[kk] = *(const short8*)(Q + base + (size_t)(qrow + lm) * 1024 + kk * 32 + quad * 8);

  f32x4 accz[4] = {};
  float m_r[4], l_r[4];
#pragma unroll
  for (int r = 0; r < 4; ++r) { m_r[r] = -1e30f; l_r[r] = 0.f; }

  for (int p0 = 0; p0 < qb + 64; p0 += 32) {
    __syncthreads();

    // Stage V^T: 256 threads x 16B coalesced load, 8 scalar LDS writes each.
    {
      const int pl = tid >> 3, h0 = (tid & 7) * 8;
      short8 v = *(const short8*)(V + base + (size_t)(p0 + pl) * 1024 + h0);
#pragma unroll
      for (int u = 0; u < 8; ++u)
        vt[(h0 + u) * 40 + pl] = ((const ushort*)&v)[u];
    }

    // Scores S[q][p] = (Q.K)/8, causal-masked.
    f32x4 S[2];
#pragma unroll
    for (int s = 0; s < 2; ++s) {
      const int prow = p0 + s * 16 + lm;
      short8 k0 = *(const short8*)(Km + base + (size_t)prow * 1024 + quad * 8);
      short8 k1 = *(const short8*)(Km + base + (size_t)prow * 1024 + 32 + quad * 8);
      f32x4 t = {0.f, 0.f, 0.f, 0.f};
      t = MFMA16(qa[0], k0, t);
      t = MFMA16(qa[1], k1, t);
#pragma unroll
      for (int r = 0; r < 4; ++r) {
        const int qg = qrow + quad * 4 + r;
        const int pg = p0 + s * 16 + lm;
        float sv = t[r] * 0.125f;
        S[s][r] = (pg > qg) ? -1e30f : sv;  // exp underflows to exactly 0
      }
    }

    // Online softmax per C-row r (row = 16 lanes of an aligned lane-group).
    float pv[2][4];
#pragma unroll
    for (int r = 0; r < 4; ++r) {
      float mx = fmaxf(S[0][r], S[1][r]);
#pragma unroll
      for (int d = 1; d < 16; d <<= 1) mx = fmaxf(mx, __shfl_xor(mx, d, 64));
      const float mn = fmaxf(m_r[r], mx);
      const float alpha = __expf(m_r[r] - mn);
      const float e0 = __expf(S[0][r] - mn);
      const float e1 = __expf(S[1][r] - mn);
      float rs = e0 + e1;
#pragma unroll
      for (int d = 1; d < 16; d <<= 1) rs += __shfl_xor(rs, d, 64);
      l_r[r] = l_r[r] * alpha + rs;
      m_r[r] = mn;
#pragma unroll
      for (int c = 0; c < 4; ++c) accz[c][r] *= alpha;
      pv[0][r] = e0;
      pv[1][r] = e1;
    }

    // P: C-layout -> LDS (bf16) -> A-layout fragment.
    ushort* pw = pb[wave];
#pragma unroll
    for (int s = 0; s < 2; ++s)
#pragma unroll
      for (int r = 0; r < 4; ++r)
        pw[(quad * 4 + r) * 40 + s * 16 + lm] = f2bf(pv[s][r]);

    __syncthreads();

    short8 pa = *(const short8*)(pw + lm * 40 + quad * 8);
#pragma unroll
    for (int c = 0; c < 4; ++c) {
      short8 vb = *(const short8*)(vt + (c * 16 + lm) * 40 + quad * 8);
      accz[c] = MFMA16(pa, vb, accz[c]);
    }
  }

#pragma unroll
  for (int c = 0; c < 4; ++c)
#pragma unroll
    for (int r = 0; r < 4; ++r)
      Z[base + (size_t)(qrow + quad * 4 + r) * 1024 + c * 16 + lm] =
          __float2bfloat16(accz[c][r] / l_r[r]);
}

extern "C" void kernel_launch(void* const* d_in, const int* in_sizes, int n_in,
                              void* d_out, int out_size, void* d_ws, size_t ws_size,
                              hipStream_t stream) {
  (void)in_sizes; (void)n_in; (void)out_size; (void)ws_size;
  const float* x  = (const float*)d_in[0];   // (4,2048,1024) fp32
  const float* wk = (const float*)d_in[1];   // (16,64,1024) fp32 -> (1024,1024)
  const float* wq = (const float*)d_in[2];
  const float* wv = (const float*)d_in[3];
  const float* wo = (const float*)d_in[4];   // (1024,1024) fp32
  float* out = (float*)d_out;                // (4,2048,1024) fp32

  // ws layout (bf16): 4 weights (2 MB each) + xb/Zb aliased (4 MB) + Q,K,V
  // (4 MB each) = 24 MB total.
  const size_t WSZ = (size_t)1024 * 1024;  // weight elements
  const size_t BS = (size_t)2048 * 1024;   // per-batch elements
  ushort* wq_b = (ushort*)d_ws;
  ushort* wk_b = wq_b + WSZ;
  ushort* wv_b = wk_b + WSZ;
  ushort* wo_b = wv_b + WSZ;
  ushort* xz_b = wo_b + WSZ;  // x before flash, Z after (lifetimes disjoint)
  ushort* Qb = xz_b + BS;
  ushort* Kb = Qb + BS;
  ushort* Vb = Kb + BS;

  const int wn4 = (int)(WSZ / 4), xn4 = (int)(BS / 4);
  const int cb = 256;
  f32_to_bf16_kernel<<<(wn4 + cb - 1) / cb, cb, 0, stream>>>(wq, wq_b, wn4);
  f32_to_bf16_kernel<<<(wn4 + cb - 1) / cb, cb, 0, stream>>>(wk, wk_b, wn4);
  f32_to_bf16_kernel<<<(wn4 + cb - 1) / cb, cb, 0, stream>>>(wv, wv_b, wn4);
  f32_to_bf16_kernel<<<(wn4 + cb - 1) / cb, cb, 0, stream>>>(wo, wo_b, wn4);

  dim3 gproj(1024 / 128, 2048 / 128);  // (N/128, M/128)
  dim3 gflash(2048 / 64, 16);

  for (int b = 0; b < 4; ++b) {
    f32_to_bf16_kernel<<<(xn4 + cb - 1) / cb, cb, 0, stream>>>(
        x + (size_t)b * BS, xz_b, xn4);
    gemm_bt_kernel<__hip_bfloat16><<<gproj, 256, 0, stream>>>(
        xz_b, wq_b, (__hip_bfloat16*)Qb, 2048, 1024, 1024);
    gemm_bt_kernel<__hip_bfloat16><<<gproj, 256, 0, stream>>>(
        xz_b, wk_b, (__hip_bfloat16*)Kb, 2048, 1024, 1024);
    gemm_bt_kernel<__hip_bfloat16><<<gproj, 256, 0, stream>>>(
        xz_b, wv_b, (__hip_bfloat16*)Vb, 2048, 1024, 1024);
    flash_kernel<<<gflash, 256, 0, stream>>>(Qb, Kb, Vb, (__hip_bfloat16*)xz_b);
    gemm_bt_kernel<float><<<gproj, 256, 0, stream>>>(
        xz_b, wo_b, out + (size_t)b * BS, 2048, 1024, 1024);
  }
}

// Round 4
// 704.579 us; speedup vs baseline: 1.6010x; 1.6010x over previous
//
#include <hip/hip_runtime.h>
#include <hip/hip_bf16.h>

// Attention forward, MI355X (gfx950). fp32 in/out, bf16 MFMA internally.
// ws (60 MB): wqkv_b[3072x1024] | wo_b[1024x1024] | xb[2048x1024] | QKV[8192x3072]
// Pipeline: 4 wt-converts; per batch {x-convert, QKV gemm}; 1 full-batch flash
// (Z written in-place over Q columns); 1 full-batch out-proj gemm (fp32 out).
// MFMA layouts (verified m89/m74):
//   A-frag: A[m=lane&15][k=(lane>>4)*8+j]; B-frag: B[n=lane&15][k=...]
//   C/D:    col=lane&15, row=(lane>>4)*4+reg

typedef short short8 __attribute__((ext_vector_type(8)));
typedef float f32x4 __attribute__((ext_vector_type(4)));

#define MFMA16(a, b, c) __builtin_amdgcn_mfma_f32_16x16x32_bf16((a), (b), (c), 0, 0, 0)

static __device__ __forceinline__ ushort f2bf(float f) {
  union { __hip_bfloat16 h; ushort u; } cv;
  cv.h = __float2bfloat16(f);
  return cv.u;
}

static __device__ __forceinline__ void store_out(float* p, float v) { *p = v; }
static __device__ __forceinline__ void store_out(__hip_bfloat16* p, float v) {
  *p = __float2bfloat16(v);
}

__global__ __launch_bounds__(256) void f32_to_bf16_kernel(
    const float* __restrict__ in, ushort* __restrict__ out, int n4) {
  int i = blockIdx.x * blockDim.x + threadIdx.x;
  if (i >= n4) return;
  const float4 v = ((const float4*)in)[i];
  ushort4 o;
  o.x = f2bf(v.x); o.y = f2bf(v.y); o.z = f2bf(v.z); o.w = f2bf(v.w);
  ((ushort4*)out)[i] = o;
}

// C[M,N] = A[M,K] * B[N,K]^T (bf16 in, fp32 acc, OUT_T out), leading dims.
// Block 256 = 4 waves; block tile 128x128, wave tile 64x64.
template <typename OUT_T>
__global__ __launch_bounds__(256) void gemm_bt_kernel(
    const ushort* __restrict__ A, int lda, const ushort* __restrict__ B, int ldb,
    OUT_T* __restrict__ C, int ldc, int M, int N, int K) {
  const int lane = threadIdx.x & 63;
  const int wave = threadIdx.x >> 6;
  const int lm = lane & 15;
  const int lk = (lane >> 4) * 8;
  const int m0 = blockIdx.y * 128 + (wave >> 1) * 64;
  const int n0 = blockIdx.x * 128 + (wave & 1) * 64;

  f32x4 acc[4][4] = {};
  for (int k0 = 0; k0 < K; k0 += 32) {
    short8 a[4], b[4];
#pragma unroll
    for (int i = 0; i < 4; ++i)
      a[i] = *(const short8*)(A + (size_t)(m0 + i * 16 + lm) * lda + k0 + lk);
#pragma unroll
    for (int i = 0; i < 4; ++i)
      b[i] = *(const short8*)(B + (size_t)(n0 + i * 16 + lm) * ldb + k0 + lk);
#pragma unroll
    for (int i = 0; i < 4; ++i)
#pragma unroll
      for (int j = 0; j < 4; ++j)
        acc[i][j] = MFMA16(a[i], b[j], acc[i][j]);
  }

  const int rq = (lane >> 4) * 4;
#pragma unroll
  for (int i = 0; i < 4; ++i)
#pragma unroll
    for (int j = 0; j < 4; ++j)
#pragma unroll
      for (int r = 0; r < 4; ++r)
        store_out(&C[(size_t)(m0 + i * 16 + rq + r) * ldc + n0 + j * 16 + lm],
                  acc[i][j][r]);
}

// Flash causal attention, all batches. QKV[8192][3072]: Q cols 0..1023,
// K cols 1024..2047, V cols 2048..3071, head h at sub-col h*64.
// Z overwrites Q in-place (each block touches only its own Q rows/cols).
// Grid (32 qblocks, 16 heads, 4 batch); block = 4 waves; wave = 16 q-rows.
// S^T = K*Q^T so each lane's scores all belong to q-row (qrow+lm):
// row softmax = 16-reg local reduce + 2 shfl_xor.  P^T -> A-layout via
// per-wave LDS (no barrier).  V^T double-buffered: 1 barrier / 64-p tile.
__global__ __launch_bounds__(256) void flash2_kernel(ushort* __restrict__ QKV) {
  constexpr int LD = 3072;
  constexpr int VS = 72;  // vt row stride (ushorts)
  constexpr int PS = 72;  // pbuf row stride
  __shared__ __align__(16) ushort vt[2][64 * VS];
  __shared__ __align__(16) ushort pbuf[4][16 * PS];

  const int qb = blockIdx.x * 64;
  const int head = blockIdx.y;
  const int b = blockIdx.z;
  const int tid = threadIdx.x;
  const int wave = tid >> 6, lane = tid & 63;
  const int lm = lane & 15, quad = lane >> 4;

  const size_t qcol = (size_t)b * 2048 * LD + head * 64;
  const size_t kcol = qcol + 1024;
  const size_t vcol = qcol + 2048;
  const int qrow = qb + wave * 16;
  const int qg = qrow + lm;  // this lane's q-row

  short8 qa[2];
#pragma unroll
  for (int kk = 0; kk < 2; ++kk)
    qa[kk] = *(const short8*)(QKV + qcol + (size_t)(qrow + lm) * LD + kk * 32 + quad * 8);

  f32x4 accz[4] = {};   // Z C-layout: row q=quad*4+r, col h=c*16+lm
  float m_l = -1e30f, l_l = 0.f;  // softmax state for row qg (replicated /quad)

  const int nt = qb / 64 + 1;
  const int h0 = (tid & 7) * 8, plb = tid >> 3;

  // stage V^T tile for iteration 'it' into buffer 'buf'
#define STAGE(it_, buf_)                                                     \
  {                                                                          \
    const int p0s = (it_) * 64;                                              \
    _Pragma("unroll") for (int rr = 0; rr < 2; ++rr) {                       \
      const int pl = plb + rr * 32;                                          \
      short8 v = *(const short8*)(QKV + vcol + (size_t)(p0s + pl) * LD + h0);\
      _Pragma("unroll") for (int u = 0; u < 8; ++u)                          \
          vt[buf_][(h0 + u) * VS + pl] = ((const ushort*)&v)[u];             \
    }                                                                        \
  }

  STAGE(0, 0)

  for (int it = 0; it < nt; ++it) {
    const int p0 = it * 64;
    __syncthreads();  // vt[it&1] writes visible; prior reads of other buf done
    if (it + 1 < nt) STAGE(it + 1, (it + 1) & 1)

    const int dq = qrow + 15 - p0;  // >= 15
    const int smax = min(4, (dq >> 4) + 1);

    float sc[4][4];
#pragma unroll
    for (int s = 0; s < 4; ++s)
#pragma unroll
      for (int r = 0; r < 4; ++r) sc[s][r] = -1e30f;

    for (int s = 0; s < smax; ++s) {
      const ushort* kp = QKV + kcol + (size_t)(p0 + s * 16 + lm) * LD;
      short8 k0 = *(const short8*)(kp + quad * 8);
      short8 k1 = *(const short8*)(kp + 32 + quad * 8);
      f32x4 t = {0.f, 0.f, 0.f, 0.f};
      t = MFMA16(k0, qa[0], t);  // D[p][q] = sum_k K[p][k] Q[q][k]
      t = MFMA16(k1, qa[1], t);
      const int pbase = p0 + s * 16 + quad * 4;
#pragma unroll
      for (int r = 0; r < 4; ++r)
        sc[s][r] = (pbase + r > qg) ? -1e30f : t[r] * 0.125f;
    }

    // row softmax (row qg): local 16-reg reduce + cross-quad shfl_xor
    float vmax = sc[0][0];
#pragma unroll
    for (int s = 0; s < 4; ++s)
#pragma unroll
      for (int r = 0; r < 4; ++r) vmax = fmaxf(vmax, sc[s][r]);
    vmax = fmaxf(vmax, __shfl_xor(vmax, 16, 64));
    vmax = fmaxf(vmax, __shfl_xor(vmax, 32, 64));
    const float mn = fmaxf(m_l, vmax);
    float rs = 0.f;
#pragma unroll
    for (int s = 0; s < 4; ++s)
#pragma unroll
      for (int r = 0; r < 4; ++r) {
        sc[s][r] = __expf(sc[s][r] - mn);  // masked/skipped -> exp(-huge)=0
        rs += sc[s][r];
      }
    rs += __shfl_xor(rs, 16, 64);
    rs += __shfl_xor(rs, 32, 64);
    const float alpha = __expf(m_l - mn);
    l_l = l_l * alpha + rs;
    m_l = mn;
#pragma unroll
    for (int r = 0; r < 4; ++r) {
      const float ar = __shfl(alpha, quad * 4 + r, 64);  // alpha of row quad*4+r
#pragma unroll
      for (int c = 0; c < 4; ++c) accz[c][r] *= ar;
    }

    // P^T (C-layout) -> per-wave LDS -> A-layout frags (same-wave, no barrier)
    ushort* pw = pbuf[wave] + lm * PS;
#pragma unroll
    for (int s = 0; s < 4; ++s)
#pragma unroll
      for (int rp = 0; rp < 2; ++rp) {
        const uint pk = (uint)f2bf(sc[s][rp * 2]) |
                        ((uint)f2bf(sc[s][rp * 2 + 1]) << 16);
        *(uint*)(pw + s * 16 + quad * 4 + rp * 2) = pk;
      }

    const int kcmax = min(2, (dq >> 5) + 1);
    for (int kc = 0; kc < kcmax; ++kc) {
      short8 pa = *(const short8*)(pw + kc * 32 + quad * 8);
#pragma unroll
      for (int c = 0; c < 4; ++c) {
        short8 vb = *(const short8*)(&vt[it & 1][(c * 16 + lm) * VS + kc * 32 + quad * 8]);
        accz[c] = MFMA16(pa, vb, accz[c]);
      }
    }
  }

  // epilogue: divide by l of row (quad*4+r), write Z over Q columns
#pragma unroll
  for (int r = 0; r < 4; ++r) {
    const float lr = __shfl(l_l, quad * 4 + r, 64);
    const float inv = 1.f / lr;
#pragma unroll
    for (int c = 0; c < 4; ++c)
      QKV[qcol + (size_t)(qrow + quad * 4 + r) * LD + c * 16 + lm] =
          f2bf(accz[c][r] * inv);
  }
#undef STAGE
}

extern "C" void kernel_launch(void* const* d_in, const int* in_sizes, int n_in,
                              void* d_out, int out_size, void* d_ws, size_t ws_size,
                              hipStream_t stream) {
  (void)in_sizes; (void)n_in; (void)out_size; (void)ws_size;
  const float* x  = (const float*)d_in[0];   // (4,2048,1024)
  const float* wk = (const float*)d_in[1];   // (16,64,1024) flat (1024,1024)
  const float* wq = (const float*)d_in[2];
  const float* wv = (const float*)d_in[3];
  const float* wo = (const float*)d_in[4];   // (1024,1024)
  float* out = (float*)d_out;

  const size_t WSZ = (size_t)1024 * 1024;
  ushort* wqkv_b = (ushort*)d_ws;            // rows 0..1023 Q, 1024.. K, 2048.. V
  ushort* wo_b = wqkv_b + 3 * WSZ;
  ushort* xb = wo_b + WSZ;                   // per-batch x (bf16)
  ushort* QKV = xb + (size_t)2048 * 1024;    // 8192 x 3072

  const int wn4 = (int)(WSZ / 4);
  const int xn4 = (int)((size_t)2048 * 1024 / 4);
  f32_to_bf16_kernel<<<(wn4 + 255) / 256, 256, 0, stream>>>(wq, wqkv_b, wn4);
  f32_to_bf16_kernel<<<(wn4 + 255) / 256, 256, 0, stream>>>(wk, wqkv_b + WSZ, wn4);
  f32_to_bf16_kernel<<<(wn4 + 255) / 256, 256, 0, stream>>>(wv, wqkv_b + 2 * WSZ, wn4);
  f32_to_bf16_kernel<<<(wn4 + 255) / 256, 256, 0, stream>>>(wo, wo_b, wn4);

  for (int b = 0; b < 4; ++b) {
    f32_to_bf16_kernel<<<(xn4 + 255) / 256, 256, 0, stream>>>(
        x + (size_t)b * 2048 * 1024, xb, xn4);
    gemm_bt_kernel<__hip_bfloat16><<<dim3(24, 16), 256, 0, stream>>>(
        xb, 1024, wqkv_b, 1024,
        (__hip_bfloat16*)(QKV + (size_t)b * 2048 * 3072), 3072, 2048, 3072, 1024);
  }

  flash2_kernel<<<dim3(32, 16, 4), 256, 0, stream>>>(QKV);

  gemm_bt_kernel<float><<<dim3(8, 64), 256, 0, stream>>>(
      QKV, 3072, wo_b, 1024, out, 1024, 8192, 1024, 1024);
}

// Round 5
// 372.781 us; speedup vs baseline: 3.0261x; 1.8901x over previous
//
#include <hip/hip_runtime.h>
#include <hip/hip_bf16.h>

// Attention forward, MI355X (gfx950). fp32 in/out, bf16 MFMA internally.
// ws (56 MB): wqkv_b[3072x1024 bf16] | wo_b[1024x1024 bf16] | QKV[8192x3072 bf16]
// Dispatches: 4 weight-converts; 1 fused QKV GEMM (fp32 A staged+converted in
// kernel); 1 flash (Z in-place over Q cols); 1 out-proj GEMM (fp32 out).
// MFMA layouts (verified m89/m74):
//   A-frag: A[m=lane&15][k=(lane>>4)*8+j]; B-frag: B[n=lane&15][k=...]
//   C/D:    col=lane&15, row=(lane>>4)*4+reg

typedef short short8 __attribute__((ext_vector_type(8)));
typedef float f32x4 __attribute__((ext_vector_type(4)));

#define MFMA16(a, b, c) __builtin_amdgcn_mfma_f32_16x16x32_bf16((a), (b), (c), 0, 0, 0)

static __device__ __forceinline__ ushort f2bf(float f) {
  union { __hip_bfloat16 h; ushort u; } cv;
  cv.h = __float2bfloat16(f);
  return cv.u;
}

static __device__ __forceinline__ void store_out(float* p, float v) { *p = v; }
static __device__ __forceinline__ void store_out(__hip_bfloat16* p, float v) {
  *p = __float2bfloat16(v);
}

__global__ __launch_bounds__(256) void f32_to_bf16_kernel(
    const float* __restrict__ in, ushort* __restrict__ out, int n4) {
  int i = blockIdx.x * blockDim.x + threadIdx.x;
  if (i >= n4) return;
  const float4 v = ((const float4*)in)[i];
  ushort4 o;
  o.x = f2bf(v.x); o.y = f2bf(v.y); o.z = f2bf(v.z); o.w = f2bf(v.w);
  ((ushort4*)out)[i] = o;
}

// C[M,N] = A[M,K] * B[N,K]^T, fp32 acc. m97 structure: 128x128 block tile,
// BK=32, LDS staging (B + bf16-A via global_load_lds width 16; fp32-A via
// VGPR cvt), ds_read_b128 fragments. Block 256 = 4 waves, wave tile 64x64.
// A_T in {ushort(bf16), float}; OUT_T in {__hip_bfloat16, float}.
template <typename A_T, typename OUT_T>
__global__ __launch_bounds__(256) void gemm_kernel(
    const A_T* __restrict__ A, int lda, const ushort* __restrict__ B, int ldb,
    OUT_T* __restrict__ C, int ldc, int K) {
  constexpr bool A_BF16 = (sizeof(A_T) == 2);
  __shared__ __align__(16) ushort As[128 * 32];
  __shared__ __align__(16) ushort Bs[128 * 32];
  const int tid = threadIdx.x;
  const int wave = tid >> 6, lane = tid & 63;
  const int lm = lane & 15, quad = lane >> 4;
  const size_t m0 = (size_t)blockIdx.y * 128;
  const size_t n0 = (size_t)blockIdx.x * 128;
  const int srow = lane >> 2;       // global_load_lds: 4 lanes/row
  const int scol = (lane & 3) * 8;

  f32x4 acc[4][4] = {};
  for (int k0 = 0; k0 < K; k0 += 32) {
    __syncthreads();  // prior compute's LDS reads done before overwrite
#pragma unroll
    for (int j = 0; j < 2; ++j) {
      const int ch = wave * 2 + j;  // 16-row chunk
      const ushort* gb = B + (n0 + ch * 16 + srow) * (size_t)ldb + k0 + scol;
      __builtin_amdgcn_global_load_lds(
          (const __attribute__((address_space(1))) void*)gb,
          (__attribute__((address_space(3))) void*)(Bs + ch * 512), 16, 0, 0);
    }
    if constexpr (A_BF16) {
#pragma unroll
      for (int j = 0; j < 2; ++j) {
        const int ch = wave * 2 + j;
        const ushort* ga = (const ushort*)A + (m0 + ch * 16 + srow) * (size_t)lda + k0 + scol;
        __builtin_amdgcn_global_load_lds(
            (const __attribute__((address_space(1))) void*)ga,
            (__attribute__((address_space(3))) void*)(As + ch * 512), 16, 0, 0);
      }
    } else {
      // fp32 A: 128x32 floats in 4 sweeps of float4/thread, cvt to bf16.
#pragma unroll
      for (int s = 0; s < 4; ++s) {
        const int idx = s * 256 + tid;
        const int r = idx >> 3, cc = (idx & 7) * 4;
        const float4 v = *(const float4*)((const float*)A + (m0 + r) * (size_t)lda + k0 + cc);
        ushort4 o;
        o.x = f2bf(v.x); o.y = f2bf(v.y); o.z = f2bf(v.z); o.w = f2bf(v.w);
        *(ushort4*)(As + r * 32 + cc) = o;
      }
    }
    __syncthreads();  // staged tile visible (compiler drains vmcnt)

    const int wm = (wave >> 1) * 64, wn = (wave & 1) * 64;
    short8 a[4], b[4];
#pragma unroll
    for (int i = 0; i < 4; ++i)
      a[i] = *(const short8*)(As + (wm + i * 16 + lm) * 32 + quad * 8);
#pragma unroll
    for (int j = 0; j < 4; ++j)
      b[j] = *(const short8*)(Bs + (wn + j * 16 + lm) * 32 + quad * 8);
#pragma unroll
    for (int i = 0; i < 4; ++i)
#pragma unroll
      for (int j = 0; j < 4; ++j)
        acc[i][j] = MFMA16(a[i], b[j], acc[i][j]);
  }

  const int wm = (wave >> 1) * 64, wn = (wave & 1) * 64;
  const int rq = quad * 4;
#pragma unroll
  for (int i = 0; i < 4; ++i)
#pragma unroll
    for (int j = 0; j < 4; ++j)
#pragma unroll
      for (int r = 0; r < 4; ++r)
        store_out(&C[(m0 + wm + i * 16 + rq + r) * (size_t)ldc + n0 + wn + j * 16 + lm],
                  acc[i][j][r]);
}

// Flash causal attention. QKV[8192][3072]: Q cols 0..1023, K 1024..2047,
// V 2048..3071; head h at sub-col h*64; row = b*2048 + pos.
// Z overwrites Q in-place. Grid (16,16,4): block handles q-tile pair
// (blockIdx.x, 31-blockIdx.x) -> exactly 33 p-tile iters per block (perfect
// balance). Block = 4 waves; wave = 16 q-rows. S^T = K*Q^T so each lane owns
// one q-row; softmax = 16-reg local reduce + 2 shfl_xor. V^T in LDS with
// XOR-swizzled stride-64 layout: addr(h,p) = h*64 + ((p>>3 ^ h>>3)<<3) + (p&7)
// -> staging writes 2-way (free), PV b128 reads conflict-free.
__global__ __launch_bounds__(256) void flash2_kernel(ushort* __restrict__ QKV) {
  constexpr int LD = 3072;
  constexpr int PS = 72;
  __shared__ __align__(16) ushort vt[2][64 * 64];
  __shared__ __align__(16) ushort pbuf[4][16 * PS];

  const int head = blockIdx.y;
  const int b = blockIdx.z;
  const int tid = threadIdx.x;
  const int wave = tid >> 6, lane = tid & 63;
  const int lm = lane & 15, quad = lane >> 4;

  const size_t qcol = (size_t)b * 2048 * LD + head * 64;
  const size_t kcol = qcol + 1024;
  const size_t vcol = qcol + 2048;

  const int h0 = (tid & 7) * 8;   // staging: this thread's 8 V-cols
  const int hsw = tid & 7;        // == h>>3 for h in [h0, h0+8)
  const int plb = tid >> 3;       // staging p base (0..31)

#define STAGE(it_, buf_)                                                      \
  {                                                                           \
    const int p0s = (it_) * 64;                                               \
    _Pragma("unroll") for (int rr = 0; rr < 2; ++rr) {                        \
      const int p = plb + rr * 32;                                            \
      short8 v = *(const short8*)(QKV + vcol + (size_t)(p0s + p) * LD + h0);  \
      ushort* dst = &vt[buf_][h0 * 64 + ((((p >> 3) ^ hsw) & 7) << 3) + (p & 7)]; \
      _Pragma("unroll") for (int u = 0; u < 8; ++u)                           \
          dst[u * 64] = ((const ushort*)&v)[u];                               \
    }                                                                         \
  }

  for (int pass = 0; pass < 2; ++pass) {
    const int qbi = (pass == 0) ? (int)blockIdx.x : 31 - (int)blockIdx.x;
    const int qb = qbi * 64;
    const int qrow = qb + wave * 16;
    const int qg = qrow + lm;  // this lane's q-row

    short8 qa[2];
#pragma unroll
    for (int kk = 0; kk < 2; ++kk)
      qa[kk] = *(const short8*)(QKV + qcol + (size_t)(qrow + lm) * LD + kk * 32 + quad * 8);

    f32x4 accz[4] = {};
    float m_l = -1e30f, l_l = 0.f;

    __syncthreads();  // prior pass's vt reads complete before restage
    STAGE(0, 0)
    const int nt = qbi + 1;

    for (int it = 0; it < nt; ++it) {
      const int p0 = it * 64;
      __syncthreads();  // staged vt[it&1] visible; prior reads of other buf done
      if (it + 1 < nt) STAGE(it + 1, (it + 1) & 1)

      const int dq = qrow + 15 - p0;  // >= 15
      const int smax = min(4, (dq >> 4) + 1);

      float sc[4][4];
#pragma unroll
      for (int s = 0; s < 4; ++s)
#pragma unroll
        for (int r = 0; r < 4; ++r) sc[s][r] = -1e30f;

      for (int s = 0; s < smax; ++s) {
        const ushort* kp = QKV + kcol + (size_t)(p0 + s * 16 + lm) * LD;
        short8 k0 = *(const short8*)(kp + quad * 8);
        short8 k1 = *(const short8*)(kp + 32 + quad * 8);
        f32x4 t = {0.f, 0.f, 0.f, 0.f};
        t = MFMA16(k0, qa[0], t);  // D[p][q]
        t = MFMA16(k1, qa[1], t);
        const int pbase = p0 + s * 16 + quad * 4;
#pragma unroll
        for (int r = 0; r < 4; ++r)
          sc[s][r] = (pbase + r > qg) ? -1e30f : t[r] * 0.125f;
      }

      float vmax = sc[0][0];
#pragma unroll
      for (int s = 0; s < 4; ++s)
#pragma unroll
        for (int r = 0; r < 4; ++r) vmax = fmaxf(vmax, sc[s][r]);
      vmax = fmaxf(vmax, __shfl_xor(vmax, 16, 64));
      vmax = fmaxf(vmax, __shfl_xor(vmax, 32, 64));
      const float mn = fmaxf(m_l, vmax);
      float rs = 0.f;
#pragma unroll
      for (int s = 0; s < 4; ++s)
#pragma unroll
        for (int r = 0; r < 4; ++r) {
          sc[s][r] = __expf(sc[s][r] - mn);
          rs += sc[s][r];
        }
      rs += __shfl_xor(rs, 16, 64);
      rs += __shfl_xor(rs, 32, 64);
      const float alpha = __expf(m_l - mn);
      l_l = l_l * alpha + rs;
      m_l = mn;
#pragma unroll
      for (int r = 0; r < 4; ++r) {
        const float ar = __shfl(alpha, quad * 4 + r, 64);
#pragma unroll
        for (int c = 0; c < 4; ++c) accz[c][r] *= ar;
      }

      // P^T (C-layout) -> per-wave LDS -> A-layout frags (same-wave)
      ushort* pw = pbuf[wave] + lm * PS;
#pragma unroll
      for (int s = 0; s < 4; ++s)
#pragma unroll
        for (int rp = 0; rp < 2; ++rp) {
          const uint pk = (uint)f2bf(sc[s][rp * 2]) |
                          ((uint)f2bf(sc[s][rp * 2 + 1]) << 16);
          *(uint*)(pw + s * 16 + quad * 4 + rp * 2) = pk;
        }

      const int kcmax = min(2, (dq >> 5) + 1);
      for (int kc = 0; kc < kcmax; ++kc) {
        short8 pa = *(const short8*)(pw + kc * 32 + quad * 8);
#pragma unroll
        for (int c = 0; c < 4; ++c) {
          const int hrow = c * 16 + lm;
          short8 vb = *(const short8*)(
              &vt[it & 1][hrow * 64 + (((4 * kc + quad) ^ (hrow >> 3)) << 3)]);
          accz[c] = MFMA16(pa, vb, accz[c]);
        }
      }
    }

#pragma unroll
    for (int r = 0; r < 4; ++r) {
      const float lr = __shfl(l_l, quad * 4 + r, 64);
      const float inv = 1.f / lr;
#pragma unroll
      for (int c = 0; c < 4; ++c)
        QKV[qcol + (size_t)(qrow + quad * 4 + r) * LD + c * 16 + lm] =
            f2bf(accz[c][r] * inv);
    }
  }
#undef STAGE
}

extern "C" void kernel_launch(void* const* d_in, const int* in_sizes, int n_in,
                              void* d_out, int out_size, void* d_ws, size_t ws_size,
                              hipStream_t stream) {
  (void)in_sizes; (void)n_in; (void)out_size; (void)ws_size;
  const float* x  = (const float*)d_in[0];   // (4,2048,1024) = (8192,1024)
  const float* wk = (const float*)d_in[1];   // (16,64,1024) flat (1024,1024)
  const float* wq = (const float*)d_in[2];
  const float* wv = (const float*)d_in[3];
  const float* wo = (const float*)d_in[4];   // (1024,1024)
  float* out = (float*)d_out;

  const size_t WSZ = (size_t)1024 * 1024;
  ushort* wqkv_b = (ushort*)d_ws;            // rows: 0..1023 Q, 1024.. K, 2048.. V
  ushort* wo_b = wqkv_b + 3 * WSZ;
  ushort* QKV = wo_b + WSZ;                  // 8192 x 3072

  const int wn4 = (int)(WSZ / 4);
  f32_to_bf16_kernel<<<(wn4 + 255) / 256, 256, 0, stream>>>(wq, wqkv_b, wn4);
  f32_to_bf16_kernel<<<(wn4 + 255) / 256, 256, 0, stream>>>(wk, wqkv_b + WSZ, wn4);
  f32_to_bf16_kernel<<<(wn4 + 255) / 256, 256, 0, stream>>>(wv, wqkv_b + 2 * WSZ, wn4);
  f32_to_bf16_kernel<<<(wn4 + 255) / 256, 256, 0, stream>>>(wo, wo_b, wn4);

  // Fused all-batch QKV projection: x(fp32, staged+converted) * Wqkv^T.
  gemm_kernel<float, __hip_bfloat16><<<dim3(24, 64), 256, 0, stream>>>(
      x, 1024, wqkv_b, 1024, (__hip_bfloat16*)QKV, 3072, 1024);

  flash2_kernel<<<dim3(16, 16, 4), 256, 0, stream>>>(QKV);

  // Out projection: Z(bf16, in QKV cols 0..1023) * Wo^T -> fp32 out.
  gemm_kernel<ushort, float><<<dim3(8, 64), 256, 0, stream>>>(
      QKV, 3072, wo_b, 1024, out, 1024, 1024);
}